// Round 2
// baseline (4769.524 us; speedup 1.0000x reference)
//
#include <hip/hip_runtime.h>

#define C_   128
#define HU_  128
#define WU_  192
#define HD_  64
#define WD_  96
#define NPIX (2 * HU_ * WU_)

__device__ __forceinline__ float wred64(float v) {
#pragma unroll
    for (int off = 32; off > 0; off >>= 1) v += __shfl_xor(v, off, 64);
    return v;
}

// LayerNorm stats for a 128-vector distributed 2 per lane
__device__ __forceinline__ void ln_stats2(float v0, float v1, float eps, float& m, float& inv) {
    float s  = wred64(v0 + v1);
    float ss = wred64(v0 * v0 + v1 * v1);
    m = s * (1.0f / 128.0f);
    float var = ss * (1.0f / 128.0f) - m * m;
    inv = rsqrtf(var + eps);
}

__device__ __forceinline__ float gelu_tanh(float x) {
    float x3 = x * x * x;
    float t  = tanhf(0.7978845608028654f * (x + 0.044715f * x3));
    return 0.5f * x * (1.0f + t);
}

__device__ __forceinline__ float gelu_erf(float x) {
    return 0.5f * x * (1.0f + erff(x * 0.7071067811865476f));
}

__global__ __launch_bounds__(64) void upsample_tf_kernel(
    const float* __restrict__ feat_map, const float* __restrict__ feat_map_up,
    const float* __restrict__ ctx_ln_b,
    const float* __restrict__ q_w, const float* __restrict__ q_b,
    const float* __restrict__ k_w, const float* __restrict__ k_b,
    const float* __restrict__ v_w, const float* __restrict__ v_b,
    const float* __restrict__ o_w, const float* __restrict__ o_b,
    const float* __restrict__ fc1_w, const float* __restrict__ fc1_b,
    const float* __restrict__ fc2_w, const float* __restrict__ fc2_b,
    const float* __restrict__ out1_w, const float* __restrict__ out1_b,
    const float* __restrict__ out2_w, const float* __restrict__ out2_b,
    const float* __restrict__ ctx_ln_g,
    float* __restrict__ out)
{
    const int n    = blockIdx.x;      // pixel id
    const int lane = threadIdx.x;     // 0..63
    const int b    = n / (HU_ * WU_);
    const int rem  = n - b * (HU_ * WU_);
    const int hu   = rem / WU_;
    const int wu   = rem - hu * WU_;
    const int c0   = 2 * lane, c1 = 2 * lane + 1;

    __shared__ float s_act[C_];
    __shared__ float s_cn[4][C_];
    __shared__ float s_q[C_];
    __shared__ float s_kk[4][C_];
    __shared__ float s_vv[4][C_];
    __shared__ float s_a[512];
    __shared__ float s_attn[16];

    int ry[2], rx[2];
    ry[0] = min(hu >> 1, HD_ - 1); ry[1] = min((hu >> 1) + 1, HD_ - 1);
    rx[0] = min(wu >> 1, WD_ - 1); rx[1] = min((wu >> 1) + 1, WD_ - 1);

    // gather context window: ctx[k2][c] = feat_map[b][c][ry][rx]
    float ctxr[4][2];
#pragma unroll
    for (int ky = 0; ky < 2; ++ky)
#pragma unroll
        for (int kx = 0; kx < 2; ++kx) {
            int k2 = ky * 2 + kx;
            int base = (b * C_) * (HD_ * WD_) + ry[ky] * WD_ + rx[kx];
            ctxr[k2][0] = feat_map[base + c0 * (HD_ * WD_)];
            ctxr[k2][1] = feat_map[base + c1 * (HD_ * WD_)];
        }

    // residual stream x
    float xr0 = feat_map_up[((b * C_ + c0) * HU_ + hu) * WU_ + wu];
    float xr1 = feat_map_up[((b * C_ + c1) * HU_ + hu) * WU_ + wu];

#pragma unroll 1
    for (int ly = 0; ly < 2; ++ly) {
        float m, inv;
        // xn = LN(x) -> s_act
        ln_stats2(xr0, xr1, 1e-6f, m, inv);
        s_act[c0] = (xr0 - m) * inv;
        s_act[c1] = (xr1 - m) * inv;
        // cn = LN(ctx, 1e-5) * g + b -> s_cn
        float g0  = ctx_ln_g[ly * C_ + c0], g1  = ctx_ln_g[ly * C_ + c1];
        float bb0 = ctx_ln_b[ly * C_ + c0], bb1 = ctx_ln_b[ly * C_ + c1];
#pragma unroll
        for (int k = 0; k < 4; ++k) {
            float mk, ik;
            ln_stats2(ctxr[k][0], ctxr[k][1], 1e-5f, mk, ik);
            s_cn[k][c0] = (ctxr[k][0] - mk) * ik * g0 + bb0;
            s_cn[k][c1] = (ctxr[k][1] - mk) * ik * g1 + bb1;
        }
        __syncthreads();

        // q = xn @ q_w + q_b (lane owns cols c0,c1)
        float qa0 = q_b[ly * C_ + c0], qa1 = q_b[ly * C_ + c1];
        {
            const float2* qwp = (const float2*)(q_w + ly * C_ * C_);
#pragma unroll 4
            for (int i = 0; i < C_; ++i) {
                float a = s_act[i];
                float2 w = qwp[i * 64 + lane];
                qa0 = fmaf(a, w.x, qa0);
                qa1 = fmaf(a, w.y, qa1);
            }
        }
        s_q[c0] = qa0;
        s_q[c1] = qa1;

        // k = cn @ k_w + k_b ; v = cn @ v_w + v_b   (4 rows each)
        {
            float ka[4][2], va[4][2];
            float kb0 = k_b[ly * C_ + c0], kb1 = k_b[ly * C_ + c1];
            float vb0 = v_b[ly * C_ + c0], vb1 = v_b[ly * C_ + c1];
#pragma unroll
            for (int k = 0; k < 4; ++k) {
                ka[k][0] = kb0; ka[k][1] = kb1;
                va[k][0] = vb0; va[k][1] = vb1;
            }
            const float2* kwp = (const float2*)(k_w + ly * C_ * C_);
            const float2* vwp = (const float2*)(v_w + ly * C_ * C_);
#pragma unroll 2
            for (int i = 0; i < C_; ++i) {
                float a0 = s_cn[0][i], a1 = s_cn[1][i], a2 = s_cn[2][i], a3 = s_cn[3][i];
                float2 kw = kwp[i * 64 + lane];
                float2 vw = vwp[i * 64 + lane];
                ka[0][0] = fmaf(a0, kw.x, ka[0][0]); ka[0][1] = fmaf(a0, kw.y, ka[0][1]);
                ka[1][0] = fmaf(a1, kw.x, ka[1][0]); ka[1][1] = fmaf(a1, kw.y, ka[1][1]);
                ka[2][0] = fmaf(a2, kw.x, ka[2][0]); ka[2][1] = fmaf(a2, kw.y, ka[2][1]);
                ka[3][0] = fmaf(a3, kw.x, ka[3][0]); ka[3][1] = fmaf(a3, kw.y, ka[3][1]);
                va[0][0] = fmaf(a0, vw.x, va[0][0]); va[0][1] = fmaf(a0, vw.y, va[0][1]);
                va[1][0] = fmaf(a1, vw.x, va[1][0]); va[1][1] = fmaf(a1, vw.y, va[1][1]);
                va[2][0] = fmaf(a2, vw.x, va[2][0]); va[2][1] = fmaf(a2, vw.y, va[2][1]);
                va[3][0] = fmaf(a3, vw.x, va[3][0]); va[3][1] = fmaf(a3, vw.y, va[3][1]);
            }
#pragma unroll
            for (int k = 0; k < 4; ++k) {
                s_kk[k][c0] = ka[k][0]; s_kk[k][c1] = ka[k][1];
                s_vv[k][c0] = va[k][0]; s_vv[k][c1] = va[k][1];
            }
        }
        __syncthreads();

        // attention scores + softmax (lanes 0..15: lane = h*4 + k2)
        if (lane < 16) {
            int h = lane >> 2, kq = lane & 3, ky = kq >> 1, kx = kq & 1;
            float dot = 0.f;
            int base = h * 32;
#pragma unroll 8
            for (int d = 0; d < 32; ++d) dot = fmaf(s_q[base + d], s_kk[kq][base + d], dot);
            float slope = exp2f(-1.1462406251802891f * (float)(h + 1));  // 24^{-(h+1)/4}
            float dyv = -(float)abs(hu - 2 * ry[ky]);
            float dxv = -(float)abs(wu - 2 * rx[kx]);
            float sim = dot * 0.17677669529663687f + slope * (dyv + dxv);
            float mx = fmaxf(sim, __shfl_xor(sim, 1, 64));
            mx = fmaxf(mx, __shfl_xor(mx, 2, 64));
            float e = expf(sim - mx);
            float ssum = e;
            ssum += __shfl_xor(ssum, 1, 64);
            ssum += __shfl_xor(ssum, 2, 64);
            s_attn[lane] = e / ssum;
        }
        __syncthreads();

        // o = attn @ v (per channel), then o -> s_act for the o-projection
        {
            int h = lane >> 4;  // head of channels c0,c1
            float o0 = 0.f, o1 = 0.f;
#pragma unroll
            for (int k = 0; k < 4; ++k) {
                float at = s_attn[h * 4 + k];
                o0 = fmaf(at, s_vv[k][c0], o0);
                o1 = fmaf(at, s_vv[k][c1], o1);
            }
            __syncthreads();
            s_act[c0] = o0;
            s_act[c1] = o1;
        }
        __syncthreads();

        // x += o @ o_w + o_b
        {
            float pa0 = o_b[ly * C_ + c0], pa1 = o_b[ly * C_ + c1];
            const float2* owp = (const float2*)(o_w + ly * C_ * C_);
#pragma unroll 4
            for (int i = 0; i < C_; ++i) {
                float a = s_act[i];
                float2 w = owp[i * 64 + lane];
                pa0 = fmaf(a, w.x, pa0);
                pa1 = fmaf(a, w.y, pa1);
            }
            xr0 += pa0;
            xr1 += pa1;
        }

        // h = LN(x) -> s_act
        ln_stats2(xr0, xr1, 1e-6f, m, inv);
        __syncthreads();
        s_act[c0] = (xr0 - m) * inv;
        s_act[c1] = (xr1 - m) * inv;
        __syncthreads();

        // fc1 (128 -> 512), gelu_tanh, store activations to s_a
        {
            float fa[8];
#pragma unroll
            for (int t = 0; t < 8; ++t) fa[t] = fc1_b[ly * 512 + 8 * lane + t];
            const float4* f1p = (const float4*)(fc1_w + ly * C_ * 512);
#pragma unroll 2
            for (int i = 0; i < C_; ++i) {
                float a = s_act[i];
                float4 u = f1p[i * 128 + 2 * lane];
                float4 v = f1p[i * 128 + 2 * lane + 1];
                fa[0] = fmaf(a, u.x, fa[0]); fa[1] = fmaf(a, u.y, fa[1]);
                fa[2] = fmaf(a, u.z, fa[2]); fa[3] = fmaf(a, u.w, fa[3]);
                fa[4] = fmaf(a, v.x, fa[4]); fa[5] = fmaf(a, v.y, fa[5]);
                fa[6] = fmaf(a, v.z, fa[6]); fa[7] = fmaf(a, v.w, fa[7]);
            }
#pragma unroll
            for (int t = 0; t < 8; ++t) s_a[8 * lane + t] = gelu_tanh(fa[t]);
        }
        __syncthreads();

        // x += act @ fc2_w + fc2_b  (512 -> 128)
        {
            float ga0 = fc2_b[ly * C_ + c0], ga1 = fc2_b[ly * C_ + c1];
            const float2* f2p = (const float2*)(fc2_w + ly * 512 * C_);
#pragma unroll 4
            for (int i = 0; i < 512; ++i) {
                float a = s_a[i];
                float2 w = f2p[i * 64 + lane];
                ga0 = fmaf(a, w.x, ga0);
                ga1 = fmaf(a, w.y, ga1);
            }
            xr0 += ga0;
            xr1 += ga1;
        }
        __syncthreads();
    }

    // final head: xf = LN(x), cf = LN(ctx) (both eps 1e-6, no affine)
    {
        float m, inv;
        ln_stats2(xr0, xr1, 1e-6f, m, inv);
        s_act[c0] = (xr0 - m) * inv;
        s_act[c1] = (xr1 - m) * inv;
#pragma unroll
        for (int k = 0; k < 4; ++k) {
            float mk, ik;
            ln_stats2(ctxr[k][0], ctxr[k][1], 1e-6f, mk, ik);
            s_cn[k][c0] = (ctxr[k][0] - mk) * ik;
            s_cn[k][c1] = (ctxr[k][1] - mk) * ik;
        }
    }
    __syncthreads();

    // h1 = gelu_exact(fin @ out1_w + out1_b); fin[r][i] built on the fly.
    // lane owns 6 consecutive output cols j0 = 6*lane.
    float acc[4][6];
#pragma unroll
    for (int j = 0; j < 6; ++j) {
        float bj = out1_b[6 * lane + j];
        acc[0][j] = bj; acc[1][j] = bj; acc[2][j] = bj; acc[3][j] = bj;
    }
    {
        const float2* o1p = (const float2*)out1_w;
#pragma unroll 1
        for (int i = 0; i < 384; ++i) {
            float f0, f1, f2, f3;
            if (i < 128) {
                float t = s_act[i];
                f0 = t; f1 = t; f2 = t; f3 = t;
            } else if (i < 256) {
                int ii = i - 128;
                f0 = s_cn[0][ii]; f1 = s_cn[1][ii]; f2 = s_cn[2][ii]; f3 = s_cn[3][ii];
            } else {
                int ii = i - 256;
                float t = s_act[ii];
                f0 = t - s_cn[0][ii]; f1 = t - s_cn[1][ii];
                f2 = t - s_cn[2][ii]; f3 = t - s_cn[3][ii];
            }
            int bi = i * 192 + 3 * lane;
            float2 wa = o1p[bi];
            float2 wb = o1p[bi + 1];
            float2 wc = o1p[bi + 2];
            float w[6] = {wa.x, wa.y, wb.x, wb.y, wc.x, wc.y};
#pragma unroll
            for (int j = 0; j < 6; ++j) {
                acc[0][j] = fmaf(f0, w[j], acc[0][j]);
                acc[1][j] = fmaf(f1, w[j], acc[1][j]);
                acc[2][j] = fmaf(f2, w[j], acc[2][j]);
                acc[3][j] = fmaf(f3, w[j], acc[3][j]);
            }
        }
    }

    // out2 matvec + softmax over K2
    {
        float w2[6];
#pragma unroll
        for (int j = 0; j < 6; ++j) w2[j] = out2_w[6 * lane + j];
        float part[4];
#pragma unroll
        for (int r = 0; r < 4; ++r) {
            float p = 0.f;
#pragma unroll
            for (int j = 0; j < 6; ++j) p = fmaf(gelu_erf(acc[r][j]), w2[j], p);
            part[r] = wred64(p);
        }
        float o2b = out2_b[0];
        float v0 = part[0] + o2b, v1 = part[1] + o2b, v2 = part[2] + o2b, v3 = part[3] + o2b;
        float mx = fmaxf(fmaxf(v0, v1), fmaxf(v2, v3));
        float e0 = expf(v0 - mx), e1 = expf(v1 - mx), e2 = expf(v2 - mx), e3 = expf(v3 - mx);
        float si = 1.0f / (e0 + e1 + e2 + e3);
        if (lane < 4) {
            float ev = (lane == 0) ? e0 : (lane == 1) ? e1 : (lane == 2) ? e2 : e3;
            out[((b * 4 + lane) * HU_ + hu) * WU_ + wu] = ev * si;
        }
    }
}

extern "C" void kernel_launch(void* const* d_in, const int* in_sizes, int n_in,
                              void* d_out, int out_size, void* d_ws, size_t ws_size,
                              hipStream_t stream) {
    const float* feat_map    = (const float*)d_in[0];
    const float* feat_map_up = (const float*)d_in[1];
    const float* ctx_ln_b    = (const float*)d_in[2];
    const float* q_w  = (const float*)d_in[3];
    const float* q_b  = (const float*)d_in[4];
    const float* k_w  = (const float*)d_in[5];
    const float* k_b  = (const float*)d_in[6];
    const float* v_w  = (const float*)d_in[7];
    const float* v_b  = (const float*)d_in[8];
    const float* o_w  = (const float*)d_in[9];
    const float* o_b  = (const float*)d_in[10];
    const float* fc1_w = (const float*)d_in[11];
    const float* fc1_b = (const float*)d_in[12];
    const float* fc2_w = (const float*)d_in[13];
    const float* fc2_b = (const float*)d_in[14];
    const float* out1_w = (const float*)d_in[15];
    const float* out1_b = (const float*)d_in[16];
    const float* out2_w = (const float*)d_in[17];
    const float* out2_b = (const float*)d_in[18];
    const float* ctx_ln_g = (const float*)d_in[19];
    float* out = (float*)d_out;

    dim3 grid(NPIX), block(64);
    upsample_tf_kernel<<<grid, block, 0, stream>>>(
        feat_map, feat_map_up, ctx_ln_b, q_w, q_b, k_w, k_b, v_w, v_b, o_w, o_b,
        fc1_w, fc1_b, fc2_w, fc2_b, out1_w, out1_b, out2_w, out2_b, ctx_ln_g, out);
}

// Round 3
// 2136.562 us; speedup vs baseline: 2.2323x; 2.2323x over previous
//
#include <hip/hip_runtime.h>

#define C_   128
#define HU_  128
#define WU_  192
#define HD_  64
#define WD_  96
#define HWD_ (HD_ * WD_)
#define NPIX (2 * HU_ * WU_)

__device__ __forceinline__ float rl(float v, int src) {
    return __int_as_float(__builtin_amdgcn_readlane(__float_as_int(v), src));
}

__device__ __forceinline__ float wred64(float v) {
#pragma unroll
    for (int off = 32; off > 0; off >>= 1) v += __shfl_xor(v, off, 64);
    return v;
}

// LayerNorm stats for a 128-vector distributed 2 per lane
__device__ __forceinline__ void ln_stats2(float v0, float v1, float eps, float& m, float& inv) {
    float s  = wred64(v0 + v1);
    float ss = wred64(v0 * v0 + v1 * v1);
    m = s * (1.0f / 128.0f);
    float var = ss * (1.0f / 128.0f) - m * m;
    inv = rsqrtf(var + eps);
}

__device__ __forceinline__ float gelu_tanh(float x) {
    float x3 = x * x * x;
    float t  = tanhf(0.7978845608028654f * (x + 0.044715f * x3));
    return 0.5f * x * (1.0f + t);
}

__device__ __forceinline__ float gelu_erf(float x) {
    return 0.5f * x * (1.0f + erff(x * 0.7071067811865476f));
}

// One wave (64 lanes) per block; each wave processes 4 consecutive pixels of one row.
// Lane owns channels c0=2*lane, c1=2*lane+1. All activation broadcasts via v_readlane
// (zero LDS, zero barriers). Weight streams amortized over 4 pixels per wave and over
// 16 co-resident waves/CU via L1.
__global__ __launch_bounds__(64, 4) void upsample_tf_kernel(
    const float* __restrict__ feat_map, const float* __restrict__ feat_map_up,
    const float* __restrict__ ctx_ln_b,
    const float* __restrict__ q_w, const float* __restrict__ q_b,
    const float* __restrict__ k_w, const float* __restrict__ k_b,
    const float* __restrict__ v_w, const float* __restrict__ v_b,
    const float* __restrict__ o_w, const float* __restrict__ o_b,
    const float* __restrict__ fc1_w, const float* __restrict__ fc1_b,
    const float* __restrict__ fc2_w, const float* __restrict__ fc2_b,
    const float* __restrict__ out1_w, const float* __restrict__ out1_b,
    const float* __restrict__ out2_w, const float* __restrict__ out2_b,
    const float* __restrict__ ctx_ln_g,
    float* __restrict__ out)
{
    const int lane = threadIdx.x;
    const int gw   = blockIdx.x;               // 0..12287
    const int n0   = gw * 4;                   // first pixel of this wave
    const int b    = n0 / (HU_ * WU_);
    const int rem  = n0 - b * (HU_ * WU_);
    const int hu   = rem / WU_;
    const int wu0  = rem - hu * WU_;           // multiple of 4; all 4 pixels share hu
    const int c0   = 2 * lane, c1 = c0 + 1;

    const int ry0 = min(hu >> 1, HD_ - 1);
    const int ry1 = min((hu >> 1) + 1, HD_ - 1);

    int rx[4][2];
#pragma unroll
    for (int p = 0; p < 4; ++p) {
        int w = wu0 + p;
        rx[p][0] = min(w >> 1, WD_ - 1);
        rx[p][1] = min((w >> 1) + 1, WD_ - 1);
    }

    // residual stream x: xr[p][slot]
    float xr[4][2];
#pragma unroll
    for (int p = 0; p < 4; ++p) {
        xr[p][0] = feat_map_up[((b * C_ + c0) * HU_ + hu) * WU_ + wu0 + p];
        xr[p][1] = feat_map_up[((b * C_ + c1) * HU_ + hu) * WU_ + wu0 + p];
    }

    const int ctx_base = b * C_ * HWD_;

#pragma unroll 1
    for (int ly = 0; ly < 2; ++ly) {
        // ---- cn = LN(ctx, 1e-5) * g + b  (reload ctx from global; L1-hot) ----
        float cn[4][4][2];
        {
            float g0  = ctx_ln_g[ly * C_ + c0], g1  = ctx_ln_g[ly * C_ + c1];
            float bb0 = ctx_ln_b[ly * C_ + c0], bb1 = ctx_ln_b[ly * C_ + c1];
#pragma unroll
            for (int p = 0; p < 4; ++p)
#pragma unroll
                for (int k = 0; k < 4; ++k) {
                    int ryk = (k >> 1) ? ry1 : ry0;
                    int base = ctx_base + ryk * WD_ + rx[p][k & 1];
                    float v0 = feat_map[base + c0 * HWD_];
                    float v1 = feat_map[base + c1 * HWD_];
                    float m, inv;
                    ln_stats2(v0, v1, 1e-5f, m, inv);
                    cn[p][k][0] = (v0 - m) * inv * g0 + bb0;
                    cn[p][k][1] = (v1 - m) * inv * g1 + bb1;
                }
        }
        // ---- xn = LN(x, 1e-6) ----
        float xn[4][2];
#pragma unroll
        for (int p = 0; p < 4; ++p) {
            float m, inv;
            ln_stats2(xr[p][0], xr[p][1], 1e-6f, m, inv);
            xn[p][0] = (xr[p][0] - m) * inv;
            xn[p][1] = (xr[p][1] - m) * inv;
        }

        // ---- q = xn @ q_w + q_b ----
        float q[4][2];
        {
            float qb0 = q_b[ly * C_ + c0], qb1 = q_b[ly * C_ + c1];
#pragma unroll
            for (int p = 0; p < 4; ++p) { q[p][0] = qb0; q[p][1] = qb1; }
            const float2* qw = (const float2*)(q_w + ly * C_ * C_);
            for (int i = 0; i < C_; i += 2) {
                int src = i >> 1;
                float2 w0 = qw[i * 64 + lane];
                float2 w1 = qw[(i + 1) * 64 + lane];
#pragma unroll
                for (int p = 0; p < 4; ++p) {
                    float a0 = rl(xn[p][0], src);
                    float a1 = rl(xn[p][1], src);
                    q[p][0] = fmaf(a0, w0.x, q[p][0]);
                    q[p][1] = fmaf(a0, w0.y, q[p][1]);
                    q[p][0] = fmaf(a1, w1.x, q[p][0]);
                    q[p][1] = fmaf(a1, w1.y, q[p][1]);
                }
            }
        }

        // ---- k = cn @ k_w + k_b ----
        float ka[4][4][2];
        {
            float kb0 = k_b[ly * C_ + c0], kb1 = k_b[ly * C_ + c1];
#pragma unroll
            for (int p = 0; p < 4; ++p)
#pragma unroll
                for (int k = 0; k < 4; ++k) { ka[p][k][0] = kb0; ka[p][k][1] = kb1; }
            const float2* kw = (const float2*)(k_w + ly * C_ * C_);
            for (int i = 0; i < C_; i += 2) {
                int src = i >> 1;
                float2 w0 = kw[i * 64 + lane];
                float2 w1 = kw[(i + 1) * 64 + lane];
#pragma unroll
                for (int p = 0; p < 4; ++p)
#pragma unroll
                    for (int k = 0; k < 4; ++k) {
                        float a0 = rl(cn[p][k][0], src);
                        float a1 = rl(cn[p][k][1], src);
                        ka[p][k][0] = fmaf(a0, w0.x, ka[p][k][0]);
                        ka[p][k][1] = fmaf(a0, w0.y, ka[p][k][1]);
                        ka[p][k][0] = fmaf(a1, w1.x, ka[p][k][0]);
                        ka[p][k][1] = fmaf(a1, w1.y, ka[p][k][1]);
                    }
            }
        }

        // ---- scores + softmax (per lane: head h = lane>>4; reduce over 16-lane group) ----
        float attn[4][4];
        {
            int h = lane >> 4;
            float slope = exp2f(-1.1462406251802891f * (float)(h + 1));  // 24^{-(h+1)/4}
            float dy0 = -(float)abs(hu - 2 * ry0);
            float dy1 = -(float)abs(hu - 2 * ry1);
#pragma unroll
            for (int p = 0; p < 4; ++p) {
                float s[4];
#pragma unroll
                for (int k = 0; k < 4; ++k)
                    s[k] = q[p][0] * ka[p][k][0] + q[p][1] * ka[p][k][1];
#pragma unroll
                for (int off = 1; off < 16; off <<= 1)
#pragma unroll
                    for (int k = 0; k < 4; ++k) s[k] += __shfl_xor(s[k], off, 64);
                int wup = wu0 + p;
#pragma unroll
                for (int k = 0; k < 4; ++k) {
                    float dyv = (k >> 1) ? dy1 : dy0;
                    float dxv = -(float)abs(wup - 2 * rx[p][k & 1]);
                    s[k] = s[k] * 0.17677669529663687f + slope * (dyv + dxv);
                }
                float mx = fmaxf(fmaxf(s[0], s[1]), fmaxf(s[2], s[3]));
                float e0 = expf(s[0] - mx), e1 = expf(s[1] - mx);
                float e2 = expf(s[2] - mx), e3 = expf(s[3] - mx);
                float si = 1.0f / (e0 + e1 + e2 + e3);
                attn[p][0] = e0 * si; attn[p][1] = e1 * si;
                attn[p][2] = e2 * si; attn[p][3] = e3 * si;
            }
        }

        // ---- v = cn @ v_w + v_b ----
        float va[4][4][2];
        {
            float vb0 = v_b[ly * C_ + c0], vb1 = v_b[ly * C_ + c1];
#pragma unroll
            for (int p = 0; p < 4; ++p)
#pragma unroll
                for (int k = 0; k < 4; ++k) { va[p][k][0] = vb0; va[p][k][1] = vb1; }
            const float2* vw = (const float2*)(v_w + ly * C_ * C_);
            for (int i = 0; i < C_; i += 2) {
                int src = i >> 1;
                float2 w0 = vw[i * 64 + lane];
                float2 w1 = vw[(i + 1) * 64 + lane];
#pragma unroll
                for (int p = 0; p < 4; ++p)
#pragma unroll
                    for (int k = 0; k < 4; ++k) {
                        float a0 = rl(cn[p][k][0], src);
                        float a1 = rl(cn[p][k][1], src);
                        va[p][k][0] = fmaf(a0, w0.x, va[p][k][0]);
                        va[p][k][1] = fmaf(a0, w0.y, va[p][k][1]);
                        va[p][k][0] = fmaf(a1, w1.x, va[p][k][0]);
                        va[p][k][1] = fmaf(a1, w1.y, va[p][k][1]);
                    }
            }
        }

        // ---- o = attn @ v ----
        float o[4][2];
#pragma unroll
        for (int p = 0; p < 4; ++p) {
            float o0 = 0.f, o1 = 0.f;
#pragma unroll
            for (int k = 0; k < 4; ++k) {
                o0 = fmaf(attn[p][k], va[p][k][0], o0);
                o1 = fmaf(attn[p][k], va[p][k][1], o1);
            }
            o[p][0] = o0; o[p][1] = o1;
        }

        // ---- x += o @ o_w + o_b ----
        {
            float pb0 = o_b[ly * C_ + c0], pb1 = o_b[ly * C_ + c1];
            float pr[4][2];
#pragma unroll
            for (int p = 0; p < 4; ++p) { pr[p][0] = pb0; pr[p][1] = pb1; }
            const float2* ow = (const float2*)(o_w + ly * C_ * C_);
            for (int i = 0; i < C_; i += 2) {
                int src = i >> 1;
                float2 w0 = ow[i * 64 + lane];
                float2 w1 = ow[(i + 1) * 64 + lane];
#pragma unroll
                for (int p = 0; p < 4; ++p) {
                    float a0 = rl(o[p][0], src);
                    float a1 = rl(o[p][1], src);
                    pr[p][0] = fmaf(a0, w0.x, pr[p][0]);
                    pr[p][1] = fmaf(a0, w0.y, pr[p][1]);
                    pr[p][0] = fmaf(a1, w1.x, pr[p][0]);
                    pr[p][1] = fmaf(a1, w1.y, pr[p][1]);
                }
            }
#pragma unroll
            for (int p = 0; p < 4; ++p) { xr[p][0] += pr[p][0]; xr[p][1] += pr[p][1]; }
        }

        // ---- hn = LN(x, 1e-6) ----
        float hn[4][2];
#pragma unroll
        for (int p = 0; p < 4; ++p) {
            float m, inv;
            ln_stats2(xr[p][0], xr[p][1], 1e-6f, m, inv);
            hn[p][0] = (xr[p][0] - m) * inv;
            hn[p][1] = (xr[p][1] - m) * inv;
        }

        // ---- fc1 (128->512) + gelu_tanh; lane owns cols 8*lane..8*lane+7 ----
        float fa[4][8];
        {
            const float4* f1b = (const float4*)(fc1_b + ly * 512);
            float4 b0 = f1b[2 * lane], b1 = f1b[2 * lane + 1];
#pragma unroll
            for (int p = 0; p < 4; ++p) {
                fa[p][0] = b0.x; fa[p][1] = b0.y; fa[p][2] = b0.z; fa[p][3] = b0.w;
                fa[p][4] = b1.x; fa[p][5] = b1.y; fa[p][6] = b1.z; fa[p][7] = b1.w;
            }
            const float4* f1p = (const float4*)(fc1_w + ly * C_ * 512);
            for (int i = 0; i < C_; i += 2) {
                int src = i >> 1;
                float4 u0 = f1p[i * 128 + 2 * lane];
                float4 u1 = f1p[i * 128 + 2 * lane + 1];
                float4 t0 = f1p[(i + 1) * 128 + 2 * lane];
                float4 t1 = f1p[(i + 1) * 128 + 2 * lane + 1];
#pragma unroll
                for (int p = 0; p < 4; ++p) {
                    float a0 = rl(hn[p][0], src);
                    float a1 = rl(hn[p][1], src);
                    fa[p][0] = fmaf(a0, u0.x, fa[p][0]); fa[p][1] = fmaf(a0, u0.y, fa[p][1]);
                    fa[p][2] = fmaf(a0, u0.z, fa[p][2]); fa[p][3] = fmaf(a0, u0.w, fa[p][3]);
                    fa[p][4] = fmaf(a0, u1.x, fa[p][4]); fa[p][5] = fmaf(a0, u1.y, fa[p][5]);
                    fa[p][6] = fmaf(a0, u1.z, fa[p][6]); fa[p][7] = fmaf(a0, u1.w, fa[p][7]);
                    fa[p][0] = fmaf(a1, t0.x, fa[p][0]); fa[p][1] = fmaf(a1, t0.y, fa[p][1]);
                    fa[p][2] = fmaf(a1, t0.z, fa[p][2]); fa[p][3] = fmaf(a1, t0.w, fa[p][3]);
                    fa[p][4] = fmaf(a1, t1.x, fa[p][4]); fa[p][5] = fmaf(a1, t1.y, fa[p][5]);
                    fa[p][6] = fmaf(a1, t1.z, fa[p][6]); fa[p][7] = fmaf(a1, t1.w, fa[p][7]);
                }
            }
#pragma unroll
            for (int p = 0; p < 4; ++p)
#pragma unroll
                for (int t = 0; t < 8; ++t) fa[p][t] = gelu_tanh(fa[p][t]);
        }

        // ---- x += act @ fc2_w + fc2_b; activation j=8*jb+t lives in lane jb, slot t ----
        {
            float gb0 = fc2_b[ly * C_ + c0], gb1 = fc2_b[ly * C_ + c1];
            float ga[4][2];
#pragma unroll
            for (int p = 0; p < 4; ++p) { ga[p][0] = gb0; ga[p][1] = gb1; }
            const float2* f2p = (const float2*)(fc2_w + ly * 512 * C_);
            for (int jb = 0; jb < 64; ++jb) {
#pragma unroll
                for (int t = 0; t < 8; ++t) {
                    float2 w = f2p[(jb * 8 + t) * 64 + lane];
#pragma unroll
                    for (int p = 0; p < 4; ++p) {
                        float a = rl(fa[p][t], jb);
                        ga[p][0] = fmaf(a, w.x, ga[p][0]);
                        ga[p][1] = fmaf(a, w.y, ga[p][1]);
                    }
                }
            }
#pragma unroll
            for (int p = 0; p < 4; ++p) { xr[p][0] += ga[p][0]; xr[p][1] += ga[p][1]; }
        }
    }  // layer loop

    // ---- final head ----
    float xf[4][2];
#pragma unroll
    for (int p = 0; p < 4; ++p) {
        float m, inv;
        ln_stats2(xr[p][0], xr[p][1], 1e-6f, m, inv);
        xf[p][0] = (xr[p][0] - m) * inv;
        xf[p][1] = (xr[p][1] - m) * inv;
    }
    float cf[4][4][2];
#pragma unroll
    for (int p = 0; p < 4; ++p)
#pragma unroll
        for (int k = 0; k < 4; ++k) {
            int ryk = (k >> 1) ? ry1 : ry0;
            int base = ctx_base + ryk * WD_ + rx[p][k & 1];
            float v0 = feat_map[base + c0 * HWD_];
            float v1 = feat_map[base + c1 * HWD_];
            float m, inv;
            ln_stats2(v0, v1, 1e-6f, m, inv);
            cf[p][k][0] = (v0 - m) * inv;
            cf[p][k][1] = (v1 - m) * inv;
        }

    // out1 cols owned: 6*lane..6*lane+5
    float bb[6], w2[6];
    {
        const float2* b1p = (const float2*)out1_b;
        float2 x0 = b1p[3 * lane], x1 = b1p[3 * lane + 1], x2 = b1p[3 * lane + 2];
        bb[0] = x0.x; bb[1] = x0.y; bb[2] = x1.x; bb[3] = x1.y; bb[4] = x2.x; bb[5] = x2.y;
        const float2* w2p = (const float2*)out2_w;
        float2 y0 = w2p[3 * lane], y1 = w2p[3 * lane + 1], y2 = w2p[3 * lane + 2];
        w2[0] = y0.x; w2[1] = y0.y; w2[2] = y1.x; w2[3] = y1.y; w2[4] = y2.x; w2[5] = y2.y;
    }
    const float o2b = out2_b[0];
    const float2* o1p = (const float2*)out1_w;

#pragma unroll
    for (int ph = 0; ph < 2; ++ph) {      // pixel pair 2*ph, 2*ph+1
        float acc[2][4][6];
#pragma unroll
        for (int p2 = 0; p2 < 2; ++p2)
#pragma unroll
            for (int r = 0; r < 4; ++r)
#pragma unroll
                for (int j = 0; j < 6; ++j) acc[p2][r][j] = bb[j];

        // rows 0..127: fin = xf (broadcast over r)
        for (int i = 0; i < 128; i += 2) {
            int src = i >> 1;
            float2 a0 = o1p[i * 192 + 3 * lane];
            float2 a1 = o1p[i * 192 + 3 * lane + 1];
            float2 a2 = o1p[i * 192 + 3 * lane + 2];
            float2 c0w = o1p[(i + 1) * 192 + 3 * lane];
            float2 c1w = o1p[(i + 1) * 192 + 3 * lane + 1];
            float2 c2w = o1p[(i + 1) * 192 + 3 * lane + 2];
            float w0[6] = {a0.x, a0.y, a1.x, a1.y, a2.x, a2.y};
            float w1[6] = {c0w.x, c0w.y, c1w.x, c1w.y, c2w.x, c2w.y};
#pragma unroll
            for (int p2 = 0; p2 < 2; ++p2) {
                float f0 = rl(xf[2 * ph + p2][0], src);
                float f1 = rl(xf[2 * ph + p2][1], src);
#pragma unroll
                for (int r = 0; r < 4; ++r)
#pragma unroll
                    for (int j = 0; j < 6; ++j) {
                        acc[p2][r][j] = fmaf(f0, w0[j], acc[p2][r][j]);
                        acc[p2][r][j] = fmaf(f1, w1[j], acc[p2][r][j]);
                    }
            }
        }
        // rows 128..255: fin = cf
        for (int i = 0; i < 128; i += 2) {
            int src = i >> 1;
            int ib = (i + 128) * 192 + 3 * lane;
            float2 a0 = o1p[ib], a1 = o1p[ib + 1], a2 = o1p[ib + 2];
            float2 d0 = o1p[ib + 192], d1 = o1p[ib + 193], d2 = o1p[ib + 194];
            float w0[6] = {a0.x, a0.y, a1.x, a1.y, a2.x, a2.y};
            float w1[6] = {d0.x, d0.y, d1.x, d1.y, d2.x, d2.y};
#pragma unroll
            for (int p2 = 0; p2 < 2; ++p2)
#pragma unroll
                for (int r = 0; r < 4; ++r) {
                    float f0 = rl(cf[2 * ph + p2][r][0], src);
                    float f1 = rl(cf[2 * ph + p2][r][1], src);
#pragma unroll
                    for (int j = 0; j < 6; ++j) {
                        acc[p2][r][j] = fmaf(f0, w0[j], acc[p2][r][j]);
                        acc[p2][r][j] = fmaf(f1, w1[j], acc[p2][r][j]);
                    }
                }
        }
        // rows 256..383: fin = xf - cf
        for (int i = 0; i < 128; i += 2) {
            int src = i >> 1;
            int ib = (i + 256) * 192 + 3 * lane;
            float2 a0 = o1p[ib], a1 = o1p[ib + 1], a2 = o1p[ib + 2];
            float2 d0 = o1p[ib + 192], d1 = o1p[ib + 193], d2 = o1p[ib + 194];
            float w0[6] = {a0.x, a0.y, a1.x, a1.y, a2.x, a2.y};
            float w1[6] = {d0.x, d0.y, d1.x, d1.y, d2.x, d2.y};
#pragma unroll
            for (int p2 = 0; p2 < 2; ++p2) {
                float x0 = rl(xf[2 * ph + p2][0], src);
                float x1 = rl(xf[2 * ph + p2][1], src);
#pragma unroll
                for (int r = 0; r < 4; ++r) {
                    float f0 = x0 - rl(cf[2 * ph + p2][r][0], src);
                    float f1 = x1 - rl(cf[2 * ph + p2][r][1], src);
#pragma unroll
                    for (int j = 0; j < 6; ++j) {
                        acc[p2][r][j] = fmaf(f0, w0[j], acc[p2][r][j]);
                        acc[p2][r][j] = fmaf(f1, w1[j], acc[p2][r][j]);
                    }
                }
            }
        }

        // gelu_erf + out2 + softmax over K2, store
#pragma unroll
        for (int p2 = 0; p2 < 2; ++p2) {
            float v[4];
#pragma unroll
            for (int r = 0; r < 4; ++r) {
                float pv = 0.f;
#pragma unroll
                for (int j = 0; j < 6; ++j) pv = fmaf(gelu_erf(acc[p2][r][j]), w2[j], pv);
                v[r] = wred64(pv) + o2b;
            }
            float mx = fmaxf(fmaxf(v[0], v[1]), fmaxf(v[2], v[3]));
            float e0 = expf(v[0] - mx), e1 = expf(v[1] - mx);
            float e2 = expf(v[2] - mx), e3 = expf(v[3] - mx);
            float si = 1.0f / (e0 + e1 + e2 + e3);
            if (lane < 4) {
                float ev = (lane == 0) ? e0 : (lane == 1) ? e1 : (lane == 2) ? e2 : e3;
                out[((b * 4 + lane) * HU_ + hu) * WU_ + wu0 + 2 * ph + p2] = ev * si;
            }
        }
    }
}

extern "C" void kernel_launch(void* const* d_in, const int* in_sizes, int n_in,
                              void* d_out, int out_size, void* d_ws, size_t ws_size,
                              hipStream_t stream) {
    const float* feat_map    = (const float*)d_in[0];
    const float* feat_map_up = (const float*)d_in[1];
    const float* ctx_ln_b    = (const float*)d_in[2];
    const float* q_w  = (const float*)d_in[3];
    const float* q_b  = (const float*)d_in[4];
    const float* k_w  = (const float*)d_in[5];
    const float* k_b  = (const float*)d_in[6];
    const float* v_w  = (const float*)d_in[7];
    const float* v_b  = (const float*)d_in[8];
    const float* o_w  = (const float*)d_in[9];
    const float* o_b  = (const float*)d_in[10];
    const float* fc1_w = (const float*)d_in[11];
    const float* fc1_b = (const float*)d_in[12];
    const float* fc2_w = (const float*)d_in[13];
    const float* fc2_b = (const float*)d_in[14];
    const float* out1_w = (const float*)d_in[15];
    const float* out1_b = (const float*)d_in[16];
    const float* out2_w = (const float*)d_in[17];
    const float* out2_b = (const float*)d_in[18];
    const float* ctx_ln_g = (const float*)d_in[19];
    float* out = (float*)d_out;

    dim3 grid(NPIX / 4), block(64);
    upsample_tf_kernel<<<grid, block, 0, stream>>>(
        feat_map, feat_map_up, ctx_ln_b, q_w, q_b, k_w, k_b, v_w, v_b, o_w, o_b,
        fc1_w, fc1_b, fc2_w, fc2_b, out1_w, out1_b, out2_w, out2_b, ctx_ln_g, out);
}